// Round 1
// baseline (1163.736 us; speedup 1.0000x reference)
//
#include <hip/hip_runtime.h>
#include <hip/hip_bf16.h>
#include <math.h>

#define N_USERS   100000
#define N_RECIPES 50000
#define NE        600000
#define NL        200000
#define DU        128
#define DR        256
#define H         128
#define OUT_D     64

// ---------------- utility fills ----------------
__global__ void fill_zero_i32(int* __restrict__ p, int n) {
  int i = blockIdx.x * 256 + threadIdx.x;
  if (i < n) p[i] = 0;
}

// ---------------- degree histogram ----------------
__global__ void hist_kernel(const int* __restrict__ esrc, const int* __restrict__ edst,
                            int* __restrict__ cnt_u, int* __restrict__ cnt_r) {
  int i = blockIdx.x * 256 + threadIdx.x;
  if (i < NE) {
    atomicAdd(&cnt_r[edst[i]], 1);
    atomicAdd(&cnt_u[esrc[i]], 1);
  }
}

// ---------------- 3-phase exclusive scan (n <= ~130k) ----------------
__global__ void scan_phaseA(const int* __restrict__ cnt, int* __restrict__ outx,
                            int* __restrict__ bsum, int n) {
  __shared__ int wsum[4];
  int tid = threadIdx.x;
  int lane = tid & 63, wid = tid >> 6;
  int idx = blockIdx.x * 4096 + tid * 16;
  int v[16];
  int s = 0;
#pragma unroll
  for (int i = 0; i < 16; ++i) {
    int x = (idx + i < n) ? cnt[idx + i] : 0;
    v[i] = s;
    s += x;
  }
  int inc = s;
#pragma unroll
  for (int o = 1; o < 64; o <<= 1) {
    int t = __shfl_up(inc, o, 64);
    if (lane >= o) inc += t;
  }
  if (lane == 63) wsum[wid] = inc;
  __syncthreads();
  int woff = 0;
#pragma unroll
  for (int w = 0; w < 4; ++w)
    if (w < wid) woff += wsum[w];
  int excl = woff + inc - s;
#pragma unroll
  for (int i = 0; i < 16; ++i)
    if (idx + i < n) outx[idx + i] = excl + v[i];
  if (tid == 255) bsum[blockIdx.x] = woff + inc;
}

__global__ void scan_phaseB(int* __restrict__ bsum, int nb, int* __restrict__ off_arr, int n) {
  int lane = threadIdx.x & 63;
  int v = (lane < nb) ? bsum[lane] : 0;
  int inc = v;
#pragma unroll
  for (int o = 1; o < 64; o <<= 1) {
    int t = __shfl_up(inc, o, 64);
    if (lane >= o) inc += t;
  }
  if (lane < nb) bsum[lane] = inc - v;  // exclusive block offset
  if (lane == 63) off_arr[n] = inc;     // grand total (=E)
}

__global__ void scan_phaseC(int* __restrict__ offx, int* __restrict__ cur,
                            const int* __restrict__ bsum, int n) {
  int i = blockIdx.x * 256 + threadIdx.x;
  if (i < n) {
    int v = offx[i] + bsum[i >> 12];
    offx[i] = v;
    cur[i] = v;
  }
}

// ---------------- scatter edge ids into CSR ----------------
__global__ void scatter_kernel(const int* __restrict__ esrc, const int* __restrict__ edst,
                               int* __restrict__ cur_u, int* __restrict__ cur_r,
                               int* __restrict__ eidx_u, int* __restrict__ eidx_r) {
  int i = blockIdx.x * 256 + threadIdx.x;
  if (i < NE) {
    int s = esrc[i], d = edst[i];
    int p = atomicAdd(&cur_r[d], 1);
    eidx_r[p] = s;
    int q = atomicAdd(&cur_u[s], 1);
    eidx_u[q] = d;
  }
}

// ---------------- segment mean: one wave per dst node ----------------
__global__ __launch_bounds__(256) void agg_mean_kernel(
    const float* __restrict__ feat, const int* __restrict__ offx,
    const int* __restrict__ eidx, float* __restrict__ outm, int n_dst) {
  int w = (blockIdx.x * 256 + threadIdx.x) >> 6;
  int lane = threadIdx.x & 63;
  if (w >= n_dst) return;
  int s = offx[w], e = offx[w + 1];
  float2 a0 = make_float2(0.f, 0.f), a1 = make_float2(0.f, 0.f);
  int i = s;
  for (; i + 1 < e; i += 2) {
    int r0 = eidx[i], r1 = eidx[i + 1];
    float2 v0 = ((const float2*)(feat + (size_t)r0 * H))[lane];
    float2 v1 = ((const float2*)(feat + (size_t)r1 * H))[lane];
    a0.x += v0.x; a0.y += v0.y;
    a1.x += v1.x; a1.y += v1.y;
  }
  if (i < e) {
    int r0 = eidx[i];
    float2 v0 = ((const float2*)(feat + (size_t)r0 * H))[lane];
    a0.x += v0.x; a0.y += v0.y;
  }
  float invc = (e > s) ? 1.f / (float)(e - s) : 0.f;
  float2 o = make_float2((a0.x + a1.x) * invc, (a0.y + a1.y) * invc);
  ((float2*)(outm + (size_t)w * H))[lane] = o;
}

// ---------------- f32 GEMM: out[M,BN] = act(A1*W1^T (+ A2*W2^T) + b) ----------------
// W is [BN,K] row-major; out[m,n] = sum_k A[m,k]*W[n,k] + b[n].
// BM=128, BK=32, 256 threads, per-thread 8x(4*NG) micro-tile, XOR-swizzled LDS.
template <int BN, bool DUAL, bool RELU>
__global__ __launch_bounds__(256) void gemm_kernel(
    const float* __restrict__ A1, const float* __restrict__ W1, int K1,
    const float* __restrict__ A2, const float* __restrict__ W2, int K2,
    const float* __restrict__ bias, float* __restrict__ outp, int M) {
  constexpr int BM = 128, BK = 32;
  constexpr int NG = BN / 64;           // column groups per thread (2 for N=128, 1 for N=64)
  constexpr int WMASK = (BN / 4) - 1;   // block-swizzle mask for Ws (31 or 15)
  __shared__ float As[BK][BM];
  __shared__ float Ws[BK][BN];
  const int tid = threadIdx.x;
  const int tx = tid & 15, ty = tid >> 4;
  const int m0 = blockIdx.x * BM;

  float4 acc[2][4][NG];
#pragma unroll
  for (int g = 0; g < 2; ++g)
#pragma unroll
    for (int i = 0; i < 4; ++i)
#pragma unroll
      for (int c = 0; c < NG; ++c) acc[g][i][c] = make_float4(0.f, 0.f, 0.f, 0.f);

  const int lr = tid >> 3;        // 0..31 (staging row)
  const int lk = (tid & 7) * 4;   // 0,4,...,28 (staging k)

#pragma unroll
  for (int pass = 0; pass < (DUAL ? 2 : 1); ++pass) {
    const float* __restrict__ A = pass ? A2 : A1;
    const float* __restrict__ W = pass ? W2 : W1;
    const int K = pass ? K2 : K1;
    for (int k0 = 0; k0 < K; k0 += BK) {
      // stage A tile (BM x BK) transposed+swizzled
#pragma unroll
      for (int rr = 0; rr < BM / 32; ++rr) {
        int m = lr + rr * 32;
        int row = m0 + m;
        float4 v = make_float4(0.f, 0.f, 0.f, 0.f);
        if (row < M) v = *(const float4*)(A + (size_t)row * K + k0 + lk);
        int m4 = m >> 2, ml = m & 3;
        As[lk + 0][(((m4) ^ ((lk + 0) & 31)) << 2) + ml] = v.x;
        As[lk + 1][(((m4) ^ ((lk + 1) & 31)) << 2) + ml] = v.y;
        As[lk + 2][(((m4) ^ ((lk + 2) & 31)) << 2) + ml] = v.z;
        As[lk + 3][(((m4) ^ ((lk + 3) & 31)) << 2) + ml] = v.w;
      }
      // stage W tile (BN x BK) transposed+swizzled
#pragma unroll
      for (int nn = 0; nn < BN / 32; ++nn) {
        int n = lr + nn * 32;
        float4 v = *(const float4*)(W + (size_t)n * K + k0 + lk);
        int n4 = n >> 2, nl = n & 3;
        Ws[lk + 0][(((n4) ^ ((lk + 0) & WMASK)) << 2) + nl] = v.x;
        Ws[lk + 1][(((n4) ^ ((lk + 1) & WMASK)) << 2) + nl] = v.y;
        Ws[lk + 2][(((n4) ^ ((lk + 2) & WMASK)) << 2) + nl] = v.z;
        Ws[lk + 3][(((n4) ^ ((lk + 3) & WMASK)) << 2) + nl] = v.w;
      }
      __syncthreads();
#pragma unroll
      for (int k = 0; k < BK; ++k) {
        float4 a0 = *(const float4*)&As[k][((ty ^ (k & 31)) << 2)];
        float4 a1 = *(const float4*)&As[k][(((16 + ty) ^ (k & 31)) << 2)];
        float4 wv[NG];
#pragma unroll
        for (int c = 0; c < NG; ++c)
          wv[c] = *(const float4*)&Ws[k][(((tx + 16 * c) ^ (k & WMASK)) << 2)];
        float ar[8] = {a0.x, a0.y, a0.z, a0.w, a1.x, a1.y, a1.z, a1.w};
#pragma unroll
        for (int g = 0; g < 2; ++g)
#pragma unroll
          for (int i = 0; i < 4; ++i) {
            float av = ar[g * 4 + i];
#pragma unroll
            for (int c = 0; c < NG; ++c) {
              acc[g][i][c].x += av * wv[c].x;
              acc[g][i][c].y += av * wv[c].y;
              acc[g][i][c].z += av * wv[c].z;
              acc[g][i][c].w += av * wv[c].w;
            }
          }
      }
      __syncthreads();
    }
  }
  // epilogue: bias (+relu), vectorized stores
  float4 bv[NG];
#pragma unroll
  for (int c = 0; c < NG; ++c) bv[c] = *(const float4*)(bias + tx * 4 + c * 64);
#pragma unroll
  for (int g = 0; g < 2; ++g)
#pragma unroll
    for (int i = 0; i < 4; ++i) {
      int row = m0 + g * 64 + ty * 4 + i;
      if (row < M) {
#pragma unroll
        for (int c = 0; c < NG; ++c) {
          float4 o;
          o.x = acc[g][i][c].x + bv[c].x;
          o.y = acc[g][i][c].y + bv[c].y;
          o.z = acc[g][i][c].z + bv[c].z;
          o.w = acc[g][i][c].w + bv[c].w;
          if (RELU) {
            o.x = fmaxf(o.x, 0.f);
            o.y = fmaxf(o.y, 0.f);
            o.z = fmaxf(o.z, 0.f);
            o.w = fmaxf(o.w, 0.f);
          }
          *(float4*)(outp + (size_t)row * BN + tx * 4 + c * 64) = o;
        }
      }
    }
}

// ---------------- decoder: one wave per label pair ----------------
__global__ __launch_bounds__(256) void decoder_kernel(
    const float* __restrict__ zu, const float* __restrict__ zr,
    const int* __restrict__ ls, const int* __restrict__ ld,
    float* __restrict__ outp) {
  int w = (blockIdx.x * 256 + threadIdx.x) >> 6;
  int lane = threadIdx.x & 63;
  if (w >= NL) return;
  float a = zu[(size_t)ls[w] * OUT_D + lane];
  float b = zr[(size_t)ld[w] * OUT_D + lane];
  float na = a * a, nb = b * b, ab = a * b;
#pragma unroll
  for (int o = 32; o > 0; o >>= 1) {
    na += __shfl_xor(na, o, 64);
    nb += __shfl_xor(nb, o, 64);
    ab += __shfl_xor(ab, o, 64);
  }
  if (lane == 0) {
    float denom = fmaxf(sqrtf(na), 1e-12f) * fmaxf(sqrtf(nb), 1e-12f);
    outp[w] = ab / denom;
  }
}

extern "C" void kernel_launch(void* const* d_in, const int* in_sizes, int n_in,
                              void* d_out, int out_size, void* d_ws, size_t ws_size,
                              hipStream_t stream) {
  (void)in_sizes; (void)n_in; (void)out_size; (void)ws_size;
  const float* x_user   = (const float*)d_in[0];
  const float* x_recipe = (const float*)d_in[1];
  const int* edge_src   = (const int*)d_in[2];
  const int* edge_dst   = (const int*)d_in[3];
  const int* lbl_src    = (const int*)d_in[4];
  const int* lbl_dst    = (const int*)d_in[5];
  const float* Wu       = (const float*)d_in[6];
  const float* bu       = (const float*)d_in[7];
  const float* Wrec     = (const float*)d_in[8];
  const float* brec     = (const float*)d_in[9];
  const float* c1_ur_Wl = (const float*)d_in[10];
  const float* c1_ur_bl = (const float*)d_in[11];
  const float* c1_ur_Wr = (const float*)d_in[12];
  const float* c1_ru_Wl = (const float*)d_in[13];
  const float* c1_ru_bl = (const float*)d_in[14];
  const float* c1_ru_Wr = (const float*)d_in[15];
  const float* c2_ur_Wl = (const float*)d_in[16];
  const float* c2_ur_bl = (const float*)d_in[17];
  const float* c2_ur_Wr = (const float*)d_in[18];
  const float* c2_ru_Wl = (const float*)d_in[19];
  const float* c2_ru_bl = (const float*)d_in[20];
  const float* c2_ru_Wr = (const float*)d_in[21];
  float* out = (float*)d_out;

  char* ws = (char*)d_ws;
  size_t off = 0;
  auto take = [&](size_t bytes) -> void* {
    void* p = ws + off;
    off = (off + bytes + 255) & ~(size_t)255;
    return p;
  };
  float* hu   = (float*)take((size_t)N_USERS * H * 4);     // 51.2 MB
  float* hr   = (float*)take((size_t)N_RECIPES * H * 4);   // 25.6 MB
  float* mean = (float*)take((size_t)N_USERS * H * 4);     // 51.2 MB (reused 4x)
  float* r1   = (float*)take((size_t)N_RECIPES * H * 4);   // 25.6 MB
  float* u1   = (float*)take((size_t)N_USERS * H * 4);     // 51.2 MB
  int* cnt_r  = (int*)take((size_t)N_RECIPES * 4);
  int* off_r  = (int*)take((size_t)(N_RECIPES + 1) * 4);
  int* cur_r  = (int*)take((size_t)N_RECIPES * 4);
  int* cnt_u  = (int*)take((size_t)N_USERS * 4);
  int* off_u  = (int*)take((size_t)(N_USERS + 1) * 4);
  int* cur_u  = (int*)take((size_t)N_USERS * 4);
  int* eidx_r = (int*)take((size_t)NE * 4);
  int* eidx_u = (int*)take((size_t)NE * 4);
  int* bsum_r = (int*)take(64 * 4);
  int* bsum_u = (int*)take(64 * 4);
  // alias final embeddings over buffers that are dead by the time they're written
  float* zr = hr;  // hr last read in agg(u1 source=hr); zr written after
  float* zu = hu;  // hu last read in u1 GEMM; zu written after

  // ---- CSR build (both directions)
  fill_zero_i32<<<(N_RECIPES + 255) / 256, 256, 0, stream>>>(cnt_r, N_RECIPES);
  fill_zero_i32<<<(N_USERS + 255) / 256, 256, 0, stream>>>(cnt_u, N_USERS);
  hist_kernel<<<(NE + 255) / 256, 256, 0, stream>>>(edge_src, edge_dst, cnt_u, cnt_r);
  int nbR = (N_RECIPES + 4095) / 4096;  // 13
  int nbU = (N_USERS + 4095) / 4096;    // 25
  scan_phaseA<<<nbR, 256, 0, stream>>>(cnt_r, off_r, bsum_r, N_RECIPES);
  scan_phaseB<<<1, 64, 0, stream>>>(bsum_r, nbR, off_r, N_RECIPES);
  scan_phaseC<<<(N_RECIPES + 255) / 256, 256, 0, stream>>>(off_r, cur_r, bsum_r, N_RECIPES);
  scan_phaseA<<<nbU, 256, 0, stream>>>(cnt_u, off_u, bsum_u, N_USERS);
  scan_phaseB<<<1, 64, 0, stream>>>(bsum_u, nbU, off_u, N_USERS);
  scan_phaseC<<<(N_USERS + 255) / 256, 256, 0, stream>>>(off_u, cur_u, bsum_u, N_USERS);
  scatter_kernel<<<(NE + 255) / 256, 256, 0, stream>>>(edge_src, edge_dst, cur_u, cur_r,
                                                       eidx_u, eidx_r);

  // ---- input projections
  gemm_kernel<128, false, false><<<(N_USERS + 127) / 128, 256, 0, stream>>>(
      x_user, Wu, DU, nullptr, nullptr, 0, bu, hu, N_USERS);
  gemm_kernel<128, false, false><<<(N_RECIPES + 127) / 128, 256, 0, stream>>>(
      x_recipe, Wrec, DR, nullptr, nullptr, 0, brec, hr, N_RECIPES);

  // ---- conv1
  agg_mean_kernel<<<(N_RECIPES * 64 + 255) / 256, 256, 0, stream>>>(hu, off_r, eidx_r, mean,
                                                                    N_RECIPES);
  gemm_kernel<128, true, true><<<(N_RECIPES + 127) / 128, 256, 0, stream>>>(
      mean, c1_ur_Wl, H, hr, c1_ur_Wr, H, c1_ur_bl, r1, N_RECIPES);
  agg_mean_kernel<<<(N_USERS * 64 + 255) / 256, 256, 0, stream>>>(hr, off_u, eidx_u, mean,
                                                                  N_USERS);
  gemm_kernel<128, true, true><<<(N_USERS + 127) / 128, 256, 0, stream>>>(
      mean, c1_ru_Wl, H, hu, c1_ru_Wr, H, c1_ru_bl, u1, N_USERS);

  // ---- conv2
  agg_mean_kernel<<<(N_RECIPES * 64 + 255) / 256, 256, 0, stream>>>(u1, off_r, eidx_r, mean,
                                                                    N_RECIPES);
  gemm_kernel<64, true, false><<<(N_RECIPES + 127) / 128, 256, 0, stream>>>(
      mean, c2_ur_Wl, H, r1, c2_ur_Wr, H, c2_ur_bl, zr, N_RECIPES);
  agg_mean_kernel<<<(N_USERS * 64 + 255) / 256, 256, 0, stream>>>(r1, off_u, eidx_u, mean,
                                                                  N_USERS);
  gemm_kernel<64, true, false><<<(N_USERS + 127) / 128, 256, 0, stream>>>(
      mean, c2_ru_Wl, H, u1, c2_ru_Wr, H, c2_ru_bl, zu, N_USERS);

  // ---- decoder
  decoder_kernel<<<(NL * 64 + 255) / 256, 256, 0, stream>>>(zu, zr, lbl_src, lbl_dst, out);
}

// Round 3
// 656.463 us; speedup vs baseline: 1.7727x; 1.7727x over previous
//
#include <hip/hip_runtime.h>
#include <hip/hip_bf16.h>
#include <math.h>

#define N_USERS   100000
#define N_RECIPES 50000
#define NE        600000
#define NL        200000
#define DU        128
#define DR        256
#define H         128
#define OUT_D     64

using half2v = __attribute__((ext_vector_type(2))) _Float16;
using half4v = __attribute__((ext_vector_type(4))) _Float16;
using half8v = __attribute__((ext_vector_type(8))) _Float16;
using f32x4  = __attribute__((ext_vector_type(4))) float;

// ---------------- utility fills ----------------
__global__ void fill_zero_i32(int* __restrict__ p, int n) {
  int i = blockIdx.x * 256 + threadIdx.x;
  if (i < n) p[i] = 0;
}

// ---------------- degree histogram ----------------
__global__ void hist_kernel(const int* __restrict__ esrc, const int* __restrict__ edst,
                            int* __restrict__ cnt_u, int* __restrict__ cnt_r) {
  int i = blockIdx.x * 256 + threadIdx.x;
  if (i < NE) {
    atomicAdd(&cnt_r[edst[i]], 1);
    atomicAdd(&cnt_u[esrc[i]], 1);
  }
}

// ---------------- 3-phase exclusive scan ----------------
__global__ void scan_phaseA(const int* __restrict__ cnt, int* __restrict__ outx,
                            int* __restrict__ bsum, int n) {
  __shared__ int wsum[4];
  int tid = threadIdx.x;
  int lane = tid & 63, wid = tid >> 6;
  int idx = blockIdx.x * 4096 + tid * 16;
  int v[16];
  int s = 0;
#pragma unroll
  for (int i = 0; i < 16; ++i) {
    int x = (idx + i < n) ? cnt[idx + i] : 0;
    v[i] = s;
    s += x;
  }
  int inc = s;
#pragma unroll
  for (int o = 1; o < 64; o <<= 1) {
    int t = __shfl_up(inc, o, 64);
    if (lane >= o) inc += t;
  }
  if (lane == 63) wsum[wid] = inc;
  __syncthreads();
  int woff = 0;
#pragma unroll
  for (int w = 0; w < 4; ++w)
    if (w < wid) woff += wsum[w];
  int excl = woff + inc - s;
#pragma unroll
  for (int i = 0; i < 16; ++i)
    if (idx + i < n) outx[idx + i] = excl + v[i];
  if (tid == 255) bsum[blockIdx.x] = woff + inc;
}

__global__ void scan_phaseB(int* __restrict__ bsum, int nb, int* __restrict__ off_arr, int n) {
  int lane = threadIdx.x & 63;
  int v = (lane < nb) ? bsum[lane] : 0;
  int inc = v;
#pragma unroll
  for (int o = 1; o < 64; o <<= 1) {
    int t = __shfl_up(inc, o, 64);
    if (lane >= o) inc += t;
  }
  if (lane < nb) bsum[lane] = inc - v;  // exclusive block offset
  if (lane == 63) off_arr[n] = inc;     // grand total (=E)
}

__global__ void scan_phaseC(int* __restrict__ offx, int* __restrict__ cur,
                            const int* __restrict__ bsum, int n) {
  int i = blockIdx.x * 256 + threadIdx.x;
  if (i < n) {
    int v = offx[i] + bsum[i >> 12];
    offx[i] = v;
    cur[i] = v;
  }
}

// ---------------- scatter edge ids into CSR ----------------
__global__ void scatter_kernel(const int* __restrict__ esrc, const int* __restrict__ edst,
                               int* __restrict__ cur_u, int* __restrict__ cur_r,
                               int* __restrict__ eidx_u, int* __restrict__ eidx_r) {
  int i = blockIdx.x * 256 + threadIdx.x;
  if (i < NE) {
    int s = esrc[i], d = edst[i];
    int p = atomicAdd(&cur_r[d], 1);
    eidx_r[p] = s;
    int q = atomicAdd(&cur_u[s], 1);
    eidx_u[q] = d;
  }
}

// ---------------- segment mean (fp16): half-wave per dst node ----------------
__global__ __launch_bounds__(256) void agg_mean_f16(
    const _Float16* __restrict__ feat, const int* __restrict__ offx,
    const int* __restrict__ eidx, _Float16* __restrict__ outm, int n_dst) {
  const int nid = (blockIdx.x * 256 + threadIdx.x) >> 5;
  const int hl = threadIdx.x & 31;
  if (nid >= n_dst) return;
  const int s = offx[nid], e = offx[nid + 1];
  float a0 = 0.f, a1 = 0.f, a2 = 0.f, a3 = 0.f;
  float b0 = 0.f, b1 = 0.f, b2 = 0.f, b3 = 0.f;
  int i = s;
  for (; i + 1 < e; i += 2) {
    const int r0 = eidx[i], r1 = eidx[i + 1];
    half4v v0 = ((const half4v*)(feat + (size_t)r0 * H))[hl];
    half4v v1 = ((const half4v*)(feat + (size_t)r1 * H))[hl];
    a0 += (float)v0[0]; a1 += (float)v0[1]; a2 += (float)v0[2]; a3 += (float)v0[3];
    b0 += (float)v1[0]; b1 += (float)v1[1]; b2 += (float)v1[2]; b3 += (float)v1[3];
  }
  if (i < e) {
    const int r0 = eidx[i];
    half4v v0 = ((const half4v*)(feat + (size_t)r0 * H))[hl];
    a0 += (float)v0[0]; a1 += (float)v0[1]; a2 += (float)v0[2]; a3 += (float)v0[3];
  }
  const float invc = (e > s) ? 1.f / (float)(e - s) : 0.f;
  half4v o;
  o[0] = (_Float16)((a0 + b0) * invc);
  o[1] = (_Float16)((a1 + b1) * invc);
  o[2] = (_Float16)((a2 + b2) * invc);
  o[3] = (_Float16)((a3 + b3) * invc);
  ((half4v*)(outm + (size_t)nid * H))[hl] = o;
}

// ---------------- fp16 MFMA GEMM: out = act(A1*W1^T (+ A2*W2^T) + b) ----------------
// W: [BN, K] f32 row-major. A: [M, K] (f32 or fp16). out: [M, BN] fp16.
// 4 waves; wave tile 64x64 = 4x4 fragments of 16x16; BK=32; LDS stride 40 halfs.
template <int WM, int WN, typename AT, bool DUAL, bool RELU>
__global__ __launch_bounds__(256) void gemm_mfma(
    const AT* __restrict__ A1, const float* __restrict__ W1, int K1,
    const AT* __restrict__ A2, const float* __restrict__ W2, int K2,
    const float* __restrict__ bias, _Float16* __restrict__ outp, int M) {
  constexpr int BM = WM * 64;
  constexpr int BN = WN * 64;
  constexpr int LDT = 40;  // padded stride in halfs (80 B): 2-way bank alias only
  __shared__ _Float16 As[BM * LDT];
  __shared__ _Float16 Ws[BN * LDT];
  const int tid = threadIdx.x;
  const int lane = tid & 63;
  const int wid = tid >> 6;
  const int wm = wid / WN;
  const int wn = wid % WN;
  const int m0 = blockIdx.x * BM;
  const int lm = lane & 15;          // fragment row/col within 16
  const int lkb = (lane >> 4) * 8;   // k element offset of this lane's 8 elems

  f32x4 acc[4][4];
  const f32x4 zero4 = {0.f, 0.f, 0.f, 0.f};
#pragma unroll
  for (int i = 0; i < 4; ++i)
#pragma unroll
    for (int j = 0; j < 4; ++j) acc[i][j] = zero4;

#pragma unroll
  for (int pass = 0; pass < (DUAL ? 2 : 1); ++pass) {
    const AT* __restrict__ A = pass ? A2 : A1;
    const float* __restrict__ W = pass ? W2 : W1;
    const int K = pass ? K2 : K1;
    for (int k0 = 0; k0 < K; k0 += 32) {
      // ---- stage A tile (BM x 32) ----
      if constexpr (sizeof(AT) == 4) {
        const int r = tid >> 3, c = (tid & 7) * 4;
#pragma unroll
        for (int p = 0; p < BM / 32; ++p) {
          const int lrow = p * 32 + r;
          const int grow = m0 + lrow;
          float4 v = make_float4(0.f, 0.f, 0.f, 0.f);
          if (grow < M) v = *(const float4*)((const float*)A + (size_t)grow * K + k0 + c);
          half4v h;
          h[0] = (_Float16)v.x; h[1] = (_Float16)v.y;
          h[2] = (_Float16)v.z; h[3] = (_Float16)v.w;
          *(half4v*)&As[lrow * LDT + c] = h;
        }
      } else {
        const int r = tid >> 2, c = (tid & 3) * 8;
#pragma unroll
        for (int p = 0; p < BM / 64; ++p) {
          const int lrow = p * 64 + r;
          const int grow = m0 + lrow;
          half8v v;
#pragma unroll
          for (int t = 0; t < 8; ++t) v[t] = (_Float16)0.f;
          if (grow < M) v = *(const half8v*)((const _Float16*)A + (size_t)grow * K + k0 + c);
          *(half8v*)&As[lrow * LDT + c] = v;
        }
      }
      // ---- stage W tile (BN x 32), f32 -> fp16 ----
      {
        const int r = tid >> 3, c = (tid & 7) * 4;
#pragma unroll
        for (int p = 0; p < BN / 32; ++p) {
          const int n = p * 32 + r;
          float4 v = *(const float4*)(W + (size_t)n * K + k0 + c);
          half4v h;
          h[0] = (_Float16)v.x; h[1] = (_Float16)v.y;
          h[2] = (_Float16)v.z; h[3] = (_Float16)v.w;
          *(half4v*)&Ws[n * LDT + c] = h;
        }
      }
      __syncthreads();
      // ---- fragments + 16 MFMA ----
      half8v af[4], bf[4];
#pragma unroll
      for (int i = 0; i < 4; ++i)
        af[i] = *(const half8v*)&As[(wm * 64 + i * 16 + lm) * LDT + lkb];
#pragma unroll
      for (int j = 0; j < 4; ++j)
        bf[j] = *(const half8v*)&Ws[(wn * 64 + j * 16 + lm) * LDT + lkb];
#pragma unroll
      for (int i = 0; i < 4; ++i)
#pragma unroll
        for (int j = 0; j < 4; ++j)
          acc[i][j] = __builtin_amdgcn_mfma_f32_16x16x32_f16(af[i], bf[j], acc[i][j], 0, 0, 0);
      __syncthreads();
    }
  }
  // ---- epilogue: bias (+relu), fp16 store. C layout: col=lane&15, row=(lane>>4)*4+reg ----
  const int rb = (lane >> 4) * 4;
#pragma unroll
  for (int j = 0; j < 4; ++j) {
    const int col = wn * 64 + j * 16 + lm;
    const float bj = bias[col];
#pragma unroll
    for (int i = 0; i < 4; ++i) {
#pragma unroll
      for (int r = 0; r < 4; ++r) {
        const int grow = m0 + wm * 64 + i * 16 + rb + r;
        if (grow < M) {
          float v = acc[i][j][r] + bj;
          if (RELU) v = fmaxf(v, 0.f);
          outp[(size_t)grow * BN + col] = (_Float16)v;
        }
      }
    }
  }
}

// ---------------- decoder: one wave per label pair (fp16 inputs) ----------------
__global__ __launch_bounds__(256) void decoder_f16(
    const _Float16* __restrict__ zu, const _Float16* __restrict__ zr,
    const int* __restrict__ ls, const int* __restrict__ ld,
    float* __restrict__ outp) {
  const int w = (blockIdx.x * 256 + threadIdx.x) >> 6;
  if (w >= NL) return;
  const int lane = threadIdx.x & 63;
  const int hl = lane & 31;
  const _Float16* src = (lane >= 32) ? (zr + (size_t)ld[w] * OUT_D)
                                     : (zu + (size_t)ls[w] * OUT_D);
  half2v v = ((const half2v*)src)[hl];
  float x0 = (float)v[0], x1 = (float)v[1];
  float y0 = __shfl_xor(x0, 32, 64);
  float y1 = __shfl_xor(x1, 32, 64);
  float nx = x0 * x0 + x1 * x1;   // lanes<32: |a|^2 part
  float ny = y0 * y0 + y1 * y1;   // lanes<32: |b|^2 part
  float ab = x0 * y0 + x1 * y1;
#pragma unroll
  for (int o = 16; o > 0; o >>= 1) {
    nx += __shfl_xor(nx, o, 64);
    ny += __shfl_xor(ny, o, 64);
    ab += __shfl_xor(ab, o, 64);
  }
  if (lane == 0) {
    float denom = fmaxf(sqrtf(nx), 1e-12f) * fmaxf(sqrtf(ny), 1e-12f);
    outp[w] = ab / denom;
  }
}

extern "C" void kernel_launch(void* const* d_in, const int* in_sizes, int n_in,
                              void* d_out, int out_size, void* d_ws, size_t ws_size,
                              hipStream_t stream) {
  (void)in_sizes; (void)n_in; (void)out_size; (void)ws_size;
  const float* x_user   = (const float*)d_in[0];
  const float* x_recipe = (const float*)d_in[1];
  const int* edge_src   = (const int*)d_in[2];
  const int* edge_dst   = (const int*)d_in[3];
  const int* lbl_src    = (const int*)d_in[4];
  const int* lbl_dst    = (const int*)d_in[5];
  const float* Wu       = (const float*)d_in[6];
  const float* bu       = (const float*)d_in[7];
  const float* Wrec     = (const float*)d_in[8];
  const float* brec     = (const float*)d_in[9];
  const float* c1_ur_Wl = (const float*)d_in[10];
  const float* c1_ur_bl = (const float*)d_in[11];
  const float* c1_ur_Wr = (const float*)d_in[12];
  const float* c1_ru_Wl = (const float*)d_in[13];
  const float* c1_ru_bl = (const float*)d_in[14];
  const float* c1_ru_Wr = (const float*)d_in[15];
  const float* c2_ur_Wl = (const float*)d_in[16];
  const float* c2_ur_bl = (const float*)d_in[17];
  const float* c2_ur_Wr = (const float*)d_in[18];
  const float* c2_ru_Wl = (const float*)d_in[19];
  const float* c2_ru_bl = (const float*)d_in[20];
  const float* c2_ru_Wr = (const float*)d_in[21];
  float* out = (float*)d_out;

  char* ws = (char*)d_ws;
  size_t off = 0;
  auto take = [&](size_t bytes) -> void* {
    void* p = ws + off;
    off = (off + bytes + 255) & ~(size_t)255;
    return p;
  };
  _Float16* hu   = (_Float16*)take((size_t)N_USERS * H * 2);    // 25.6 MB
  _Float16* hr   = (_Float16*)take((size_t)N_RECIPES * H * 2);  // 12.8 MB
  _Float16* mean = (_Float16*)take((size_t)N_USERS * H * 2);    // 25.6 MB (reused 4x)
  _Float16* r1   = (_Float16*)take((size_t)N_RECIPES * H * 2);
  _Float16* u1   = (_Float16*)take((size_t)N_USERS * H * 2);
  int* cnt_r  = (int*)take((size_t)N_RECIPES * 4);
  int* off_r  = (int*)take((size_t)(N_RECIPES + 1) * 4);
  int* cur_r  = (int*)take((size_t)N_RECIPES * 4);
  int* cnt_u  = (int*)take((size_t)N_USERS * 4);
  int* off_u  = (int*)take((size_t)(N_USERS + 1) * 4);
  int* cur_u  = (int*)take((size_t)N_USERS * 4);
  int* eidx_r = (int*)take((size_t)NE * 4);
  int* eidx_u = (int*)take((size_t)NE * 4);
  int* bsum_r = (int*)take(64 * 4);
  int* bsum_u = (int*)take(64 * 4);
  // final embeddings alias buffers dead by the time they're written
  _Float16* zr = hr;  // hr last read in agg for u1; zr written after
  _Float16* zu = hu;  // hu last read in u1 GEMM; zu written after

  // ---- CSR build (both directions)
  fill_zero_i32<<<(N_RECIPES + 255) / 256, 256, 0, stream>>>(cnt_r, N_RECIPES);
  fill_zero_i32<<<(N_USERS + 255) / 256, 256, 0, stream>>>(cnt_u, N_USERS);
  hist_kernel<<<(NE + 255) / 256, 256, 0, stream>>>(edge_src, edge_dst, cnt_u, cnt_r);
  int nbR = (N_RECIPES + 4095) / 4096;  // 13
  int nbU = (N_USERS + 4095) / 4096;    // 25
  scan_phaseA<<<nbR, 256, 0, stream>>>(cnt_r, off_r, bsum_r, N_RECIPES);
  scan_phaseB<<<1, 64, 0, stream>>>(bsum_r, nbR, off_r, N_RECIPES);
  scan_phaseC<<<(N_RECIPES + 255) / 256, 256, 0, stream>>>(off_r, cur_r, bsum_r, N_RECIPES);
  scan_phaseA<<<nbU, 256, 0, stream>>>(cnt_u, off_u, bsum_u, N_USERS);
  scan_phaseB<<<1, 64, 0, stream>>>(bsum_u, nbU, off_u, N_USERS);
  scan_phaseC<<<(N_USERS + 255) / 256, 256, 0, stream>>>(off_u, cur_u, bsum_u, N_USERS);
  scatter_kernel<<<(NE + 255) / 256, 256, 0, stream>>>(edge_src, edge_dst, cur_u, cur_r,
                                                       eidx_u, eidx_r);

  // ---- input projections (f32 A, converted in staging)
  gemm_mfma<2, 2, float, false, false><<<(N_USERS + 127) / 128, 256, 0, stream>>>(
      x_user, Wu, DU, (const float*)nullptr, nullptr, 0, bu, hu, N_USERS);
  gemm_mfma<2, 2, float, false, false><<<(N_RECIPES + 127) / 128, 256, 0, stream>>>(
      x_recipe, Wrec, DR, (const float*)nullptr, nullptr, 0, brec, hr, N_RECIPES);

  // ---- conv1
  agg_mean_f16<<<(N_RECIPES * 32 + 255) / 256, 256, 0, stream>>>(hu, off_r, eidx_r, mean,
                                                                 N_RECIPES);
  gemm_mfma<2, 2, _Float16, true, true><<<(N_RECIPES + 127) / 128, 256, 0, stream>>>(
      mean, c1_ur_Wl, H, hr, c1_ur_Wr, H, c1_ur_bl, r1, N_RECIPES);
  agg_mean_f16<<<(N_USERS * 32 + 255) / 256, 256, 0, stream>>>(hr, off_u, eidx_u, mean,
                                                               N_USERS);
  gemm_mfma<2, 2, _Float16, true, true><<<(N_USERS + 127) / 128, 256, 0, stream>>>(
      mean, c1_ru_Wl, H, hu, c1_ru_Wr, H, c1_ru_bl, u1, N_USERS);

  // ---- conv2 (BN=64: BM=256, 4x1 waves)
  agg_mean_f16<<<(N_RECIPES * 32 + 255) / 256, 256, 0, stream>>>(u1, off_r, eidx_r, mean,
                                                                 N_RECIPES);
  gemm_mfma<4, 1, _Float16, true, false><<<(N_RECIPES + 255) / 256, 256, 0, stream>>>(
      mean, c2_ur_Wl, H, r1, c2_ur_Wr, H, c2_ur_bl, zr, N_RECIPES);
  agg_mean_f16<<<(N_USERS * 32 + 255) / 256, 256, 0, stream>>>(r1, off_u, eidx_u, mean,
                                                               N_USERS);
  gemm_mfma<4, 1, _Float16, true, false><<<(N_USERS + 255) / 256, 256, 0, stream>>>(
      mean, c2_ru_Wl, H, u1, c2_ru_Wr, H, c2_ru_bl, zu, N_USERS);

  // ---- decoder
  decoder_f16<<<((size_t)NL * 64 + 255) / 256, 256, 0, stream>>>(zu, zr, lbl_src, lbl_dst, out);
}